// Round 5
// baseline (1829.329 us; speedup 1.0000x reference)
//
#include <hip/hip_runtime.h>
#include <hip/hip_bf16.h>
#include <math.h>

#define F 128
#define H 256
#define C 40
#define KHOPS 10
#define TM 64
#define HK 64

// ---------------- CSR build ----------------
__global__ void k_count(const int* __restrict__ dst, int E, int* __restrict__ cnt) {
    int e = blockIdx.x * 256 + threadIdx.x;
    if (e < E) atomicAdd(&cnt[dst[e]], 1);
}

__global__ void k_scan1(const int* __restrict__ cnt, int n, int* __restrict__ bsum) {
    __shared__ int sh[256];
    int t = threadIdx.x;
    int base = blockIdx.x * 4096 + t * 16;
    int s = 0;
    for (int i = 0; i < 16; i++) { int idx = base + i; if (idx < n) s += cnt[idx]; }
    sh[t] = s; __syncthreads();
    for (int o = 128; o > 0; o >>= 1) {
        if (t < o) sh[t] += sh[t + o];
        __syncthreads();
    }
    if (t == 0) bsum[blockIdx.x] = sh[0];
}

__global__ void k_scan2(int* __restrict__ bsum, int nb) {
    if (threadIdx.x == 0) {
        int acc = 0;
        for (int i = 0; i < nb; i++) { int v = bsum[i]; bsum[i] = acc; acc += v; }
    }
}

__global__ void k_scan3(const int* __restrict__ cnt, int n, const int* __restrict__ bsum,
                        int* __restrict__ rp) {
    __shared__ int sh[256];
    int t = threadIdx.x;
    int base = blockIdx.x * 4096 + t * 16;
    int local[16]; int s = 0;
    for (int i = 0; i < 16; i++) {
        int idx = base + i;
        int v = (idx < n) ? cnt[idx] : 0;
        local[i] = v; s += v;
    }
    sh[t] = s; __syncthreads();
    for (int o = 1; o < 256; o <<= 1) {
        int v = (t >= o) ? sh[t - o] : 0;
        __syncthreads();
        sh[t] += v;
        __syncthreads();
    }
    int excl = (t == 0) ? 0 : sh[t - 1];
    int run = bsum[blockIdx.x] + excl;
    for (int i = 0; i < 16; i++) {
        int idx = base + i;
        if (idx < n) { rp[idx] = run; run += local[i]; }
    }
}

__global__ void k_fill(const int* __restrict__ src, const int* __restrict__ dst,
                       const float* __restrict__ nrm, int E, const int* __restrict__ rp,
                       int* __restrict__ cur, int2* __restrict__ ep) {
    int e = blockIdx.x * 256 + threadIdx.x;
    if (e < E) {
        int d = dst[e];
        int p = rp[d] + atomicAdd(&cur[d], 1);
        ep[p] = make_int2(src[e], __float_as_int(nrm[e]));
    }
}

// ---------------- W2 transpose: [H][C] -> [C][H] ----------------
__global__ void k_wt(const float* __restrict__ W2, float* __restrict__ w2t) {
    int t = blockIdx.x * 256 + threadIdx.x;
    if (t < H * C) { int h = t / C, c = t % C; w2t[c * H + h] = W2[t]; }
}

// ------- fused MLP: Linear(128->256)+BN+ReLU+Linear(256->40) + snapshot-0 combine -------
__launch_bounds__(256, 3)
__global__ void k_mlp(const float* __restrict__ x, const float* __restrict__ W1,
                      const float* __restrict__ b1, const float* __restrict__ g,
                      const float* __restrict__ be, const float* __restrict__ mu,
                      const float* __restrict__ var, const float* __restrict__ w2t,
                      const float* __restrict__ b2, const float* __restrict__ pw,
                      const float* __restrict__ pb,
                      float* __restrict__ hbuf, int cp, float* __restrict__ oacc, int N) {
    __shared__ float xs[TM][132];   // [node][f]; rows tn+16i share bank offset -> 2-way max
    __shared__ float h1s[TM][68];   // [node][hh]; reused as epilogue scratch
    __shared__ float asc[HK], dsc[HK];
    __shared__ float redc[256];
    __shared__ float sigv[TM];

    int t = threadIdx.x;
    int n0 = blockIdx.x * TM;

    // stage x tile (coalesced global, natural LDS layout)
    for (int k = 0; k < 8; k++) {
        int idx = k * 256 + t;          // over 2048 float4
        int node = idx >> 5, f4 = idx & 31;
        int n = n0 + node;
        float4 v = (n < N) ? ((const float4*)x)[(size_t)n * (F / 4) + f4]
                           : make_float4(0.f, 0.f, 0.f, 0.f);
        *((float4*)&xs[node][f4 * 4]) = v;
    }

    float acc2[10];
    {
        int cg = t & 3;
        #pragma unroll
        for (int j = 0; j < 10; j++) acc2[j] = b2[cg * 10 + j];
    }

    int tn = t & 15, th = t >> 4;
    const float4* W1g = (const float4*)W1;   // [F][H/4]
    const float4* w2t4 = (const float4*)w2t; // [C][H/4]

    for (int h0 = 0; h0 < H; h0 += HK) {
        // fused BN scale/shift (includes b1)
        if (t < HK) {
            int hg = h0 + t;
            float a = g[hg] * rsqrtf(var[hg] + 1e-5f);
            asc[t] = a;
            dsc[t] = (b1[hg] - mu[hg]) * a + be[hg];
        }
        __syncthreads();

        // stage 1: x @ W1 chunk (W1 from global: 16-lane broadcast b128, L2-hot)
        float acc[4][4];
        #pragma unroll
        for (int i = 0; i < 4; i++)
            #pragma unroll
            for (int j = 0; j < 4; j++) acc[i][j] = 0.f;

        #pragma unroll 4
        for (int f0 = 0; f0 < F; f0 += 4) {
            float4 wv[4];
            #pragma unroll
            for (int q = 0; q < 4; q++)
                wv[q] = W1g[(size_t)(f0 + q) * (H / 4) + (h0 >> 2) + th];
            float4 xv[4];
            #pragma unroll
            for (int i = 0; i < 4; i++)
                xv[i] = *((const float4*)&xs[tn + 16 * i][f0]);
            #pragma unroll
            for (int i = 0; i < 4; i++) {
                float xa[4] = {xv[i].x, xv[i].y, xv[i].z, xv[i].w};
                #pragma unroll
                for (int q = 0; q < 4; q++) {
                    float wa[4] = {wv[q].x, wv[q].y, wv[q].z, wv[q].w};
                    #pragma unroll
                    for (int j = 0; j < 4; j++) acc[i][j] += xa[q] * wa[j];
                }
            }
        }
        // BN + ReLU -> h1s
        #pragma unroll
        for (int i = 0; i < 4; i++) {
            float4 o;
            float* po = (float*)&o;
            #pragma unroll
            for (int j = 0; j < 4; j++) {
                int hh = th * 4 + j;
                float v = acc[i][j] * asc[hh] + dsc[hh];
                po[j] = v > 0.f ? v : 0.f;
            }
            *((float4*)&h1s[tn + 16 * i][th * 4]) = o;
        }
        __syncthreads();

        // stage 2: h1 chunk @ W2 chunk (W2^T from global scratch, broadcast b128)
        int n_loc = t >> 2, cg = t & 3;
        #pragma unroll 4
        for (int hh = 0; hh < HK; hh += 4) {
            float4 hv = *((const float4*)&h1s[n_loc][hh]);
            #pragma unroll
            for (int j = 0; j < 10; j++) {
                float4 w4 = w2t4[(size_t)(cg * 10 + j) * (H / 4) + ((h0 + hh) >> 2)];
                acc2[j] += hv.x * w4.x + hv.y * w4.y + hv.z * w4.z + hv.w * w4.w;
            }
        }
        __syncthreads();
    }

    // epilogue: stash h into LDS, sigmoid per node, write padded h row + out init
    int n_loc = t >> 2, cg = t & 3;
    #pragma unroll
    for (int j = 0; j < 10; j++) h1s[n_loc][cg * 10 + j] = acc2[j];
    float part = 0.f;
    #pragma unroll
    for (int j = 0; j < 10; j++) part += acc2[j] * pw[cg * 10 + j];
    redc[t] = part;
    __syncthreads();
    if (cg == 0) {
        float s = redc[n_loc * 4] + redc[n_loc * 4 + 1] + redc[n_loc * 4 + 2] + redc[n_loc * 4 + 3];
        sigv[n_loc] = 1.f / (1.f + expf(-(s + pb[0])));
    }
    __syncthreads();
    for (int k = 0; k < 2; k++) {
        int idx = k * 256 + t;          // 320 pack tasks: 64 rows x 5 packs of 8 floats
        if (idx < 320) {
            int row = idx / 5, p = idx % 5;
            int n = n0 + row;
            if (n < N) {
                float4 a, b;
                a.x = h1s[row][8 * p + 0]; a.y = h1s[row][8 * p + 1];
                a.z = h1s[row][8 * p + 2]; a.w = h1s[row][8 * p + 3];
                b.x = h1s[row][8 * p + 4]; b.y = h1s[row][8 * p + 5];
                b.z = h1s[row][8 * p + 6]; b.w = h1s[row][8 * p + 7];
                float4* hp = (float4*)(hbuf + (size_t)n * cp + 8 * p);
                hp[0] = a; hp[1] = b;
                float sg = sigv[row];
                float4 oa, ob;
                oa.x = sg * a.x; oa.y = sg * a.y; oa.z = sg * a.z; oa.w = sg * a.w;
                ob.x = sg * b.x; ob.y = sg * b.y; ob.z = sg * b.z; ob.w = sg * b.w;
                float4* op = (float4*)(oacc + (size_t)n * C + 8 * p);
                op[0] = oa; op[1] = ob;
            }
        }
    }
}

// ---------------- one propagation hop, fused with retain-combine ----------------
// 320 threads: 64 nodes/block, 5 lanes/node, 2 float4 per lane. Rows stride cp4 float4s.
__global__ void k_hop(const float4* __restrict__ cur4, float4* __restrict__ nxt4,
                      float4* __restrict__ oacc4, const int* __restrict__ rp,
                      const int2* __restrict__ ep, int cp4,
                      const float* __restrict__ pw, const float* __restrict__ pb, int N) {
    __shared__ float red[320];
    __shared__ float sig[64];
    int t = threadIdx.x;
    int nl = t / 5, p = t % 5;
    int n = blockIdx.x * 64 + nl;
    int c0 = 2 * p;
    float4 a0 = make_float4(0.f, 0.f, 0.f, 0.f);
    float4 a1 = make_float4(0.f, 0.f, 0.f, 0.f);
    if (n < N) {
        int b = rp[n], e = rp[n + 1];
        int j = b;
        for (; j + 4 <= e; j += 4) {
            int2 e0 = ep[j], e1 = ep[j + 1], e2 = ep[j + 2], e3 = ep[j + 3];
            const float4* r0 = cur4 + (size_t)e0.x * cp4 + c0;
            const float4* r1 = cur4 + (size_t)e1.x * cp4 + c0;
            const float4* r2 = cur4 + (size_t)e2.x * cp4 + c0;
            const float4* r3 = cur4 + (size_t)e3.x * cp4 + c0;
            float4 v00 = r0[0], v01 = r0[1];
            float4 v10 = r1[0], v11 = r1[1];
            float4 v20 = r2[0], v21 = r2[1];
            float4 v30 = r3[0], v31 = r3[1];
            float w0 = __int_as_float(e0.y), w1 = __int_as_float(e1.y);
            float w2 = __int_as_float(e2.y), w3 = __int_as_float(e3.y);
            a0.x += w0 * v00.x; a0.y += w0 * v00.y; a0.z += w0 * v00.z; a0.w += w0 * v00.w;
            a1.x += w0 * v01.x; a1.y += w0 * v01.y; a1.z += w0 * v01.z; a1.w += w0 * v01.w;
            a0.x += w1 * v10.x; a0.y += w1 * v10.y; a0.z += w1 * v10.z; a0.w += w1 * v10.w;
            a1.x += w1 * v11.x; a1.y += w1 * v11.y; a1.z += w1 * v11.z; a1.w += w1 * v11.w;
            a0.x += w2 * v20.x; a0.y += w2 * v20.y; a0.z += w2 * v20.z; a0.w += w2 * v20.w;
            a1.x += w2 * v21.x; a1.y += w2 * v21.y; a1.z += w2 * v21.z; a1.w += w2 * v21.w;
            a0.x += w3 * v30.x; a0.y += w3 * v30.y; a0.z += w3 * v30.z; a0.w += w3 * v30.w;
            a1.x += w3 * v31.x; a1.y += w3 * v31.y; a1.z += w3 * v31.z; a1.w += w3 * v31.w;
        }
        if (j + 2 <= e) {
            int2 e0 = ep[j], e1 = ep[j + 1];
            const float4* r0 = cur4 + (size_t)e0.x * cp4 + c0;
            const float4* r1 = cur4 + (size_t)e1.x * cp4 + c0;
            float4 v00 = r0[0], v01 = r0[1];
            float4 v10 = r1[0], v11 = r1[1];
            float w0 = __int_as_float(e0.y), w1 = __int_as_float(e1.y);
            a0.x += w0 * v00.x; a0.y += w0 * v00.y; a0.z += w0 * v00.z; a0.w += w0 * v00.w;
            a1.x += w0 * v01.x; a1.y += w0 * v01.y; a1.z += w0 * v01.z; a1.w += w0 * v01.w;
            a0.x += w1 * v10.x; a0.y += w1 * v10.y; a0.z += w1 * v10.z; a0.w += w1 * v10.w;
            a1.x += w1 * v11.x; a1.y += w1 * v11.y; a1.z += w1 * v11.z; a1.w += w1 * v11.w;
            j += 2;
        }
        if (j < e) {
            int2 e0 = ep[j];
            const float4* r0 = cur4 + (size_t)e0.x * cp4 + c0;
            float4 v00 = r0[0], v01 = r0[1];
            float w0 = __int_as_float(e0.y);
            a0.x += w0 * v00.x; a0.y += w0 * v00.y; a0.z += w0 * v00.z; a0.w += w0 * v00.w;
            a1.x += w0 * v01.x; a1.y += w0 * v01.y; a1.z += w0 * v01.z; a1.w += w0 * v01.w;
        }
        nxt4[(size_t)n * cp4 + c0] = a0;
        nxt4[(size_t)n * cp4 + c0 + 1] = a1;
    }
    // retain-combine
    float4 pw0 = ((const float4*)pw)[c0];
    float4 pw1 = ((const float4*)pw)[c0 + 1];
    red[t] = a0.x * pw0.x + a0.y * pw0.y + a0.z * pw0.z + a0.w * pw0.w
           + a1.x * pw1.x + a1.y * pw1.y + a1.z * pw1.z + a1.w * pw1.w;
    __syncthreads();
    if (p == 0) {
        float s = red[t] + red[t + 1] + red[t + 2] + red[t + 3] + red[t + 4];
        sig[nl] = 1.f / (1.f + expf(-(s + pb[0])));
    }
    __syncthreads();
    if (n < N) {
        float sg = sig[nl];
        size_t o = (size_t)n * 10 + c0;      // oacc packed [N][40]
        float4 v0 = oacc4[o], v1 = oacc4[o + 1];
        v0.x += sg * a0.x; v0.y += sg * a0.y; v0.z += sg * a0.z; v0.w += sg * a0.w;
        v1.x += sg * a1.x; v1.y += sg * a1.y; v1.z += sg * a1.z; v1.w += sg * a1.w;
        oacc4[o] = v0;
        oacc4[o + 1] = v1;
    }
}

// ---------------- in-place log_softmax over C (float4) ----------------
__global__ void k_lsm(float4* __restrict__ io, int N) {
    __shared__ float red[320];
    __shared__ float statm[32];
    __shared__ float stats[32];
    int t = threadIdx.x;
    int nl = t / 10, c4 = t % 10;
    int n = blockIdx.x * 32 + nl;
    bool ok = n < N;
    float4 v = ok ? io[(size_t)n * 10 + c4] : make_float4(-1e30f, -1e30f, -1e30f, -1e30f);
    red[t] = fmaxf(fmaxf(v.x, v.y), fmaxf(v.z, v.w));
    __syncthreads();
    if (c4 == 0) {
        float m = -1e30f;
        #pragma unroll
        for (int q = 0; q < 10; q++) m = fmaxf(m, red[nl * 10 + q]);
        statm[nl] = m;
    }
    __syncthreads();
    float m = statm[nl];
    float e0 = expf(v.x - m), e1 = expf(v.y - m), e2 = expf(v.z - m), e3 = expf(v.w - m);
    red[t] = e0 + e1 + e2 + e3;
    __syncthreads();
    if (c4 == 0) {
        float s = 0.f;
        #pragma unroll
        for (int q = 0; q < 10; q++) s += red[nl * 10 + q];
        stats[nl] = logf(s);
    }
    __syncthreads();
    if (ok) {
        float ls = stats[nl];
        io[(size_t)n * 10 + c4] = make_float4(v.x - m - ls, v.y - m - ls, v.z - m - ls, v.w - m - ls);
    }
}

extern "C" void kernel_launch(void* const* d_in, const int* in_sizes, int n_in,
                              void* d_out, int out_size, void* d_ws, size_t ws_size,
                              hipStream_t stream) {
    const float* x   = (const float*)d_in[0];
    const int*   ei  = (const int*)d_in[1];     // [2,E]: src row then dst row
    const float* nrm = (const float*)d_in[2];
    const float* W1  = (const float*)d_in[3];
    const float* b1  = (const float*)d_in[4];
    const float* g   = (const float*)d_in[5];
    const float* be  = (const float*)d_in[6];
    const float* mu  = (const float*)d_in[7];
    const float* var = (const float*)d_in[8];
    const float* W2  = (const float*)d_in[9];
    const float* b2  = (const float*)d_in[10];
    const float* pw  = (const float*)d_in[11];
    const float* pb  = (const float*)d_in[12];
    float* out = (float*)d_out;

    int N = in_sizes[0] / F;
    int E = in_sizes[2];

    auto alup = [](size_t b) { return ((b + 255) / 256) * 256; };
    size_t fixedB = alup((size_t)(N + 1) * 4) * 2 + alup(1024) + alup((size_t)E * 8)
                  + alup((size_t)H * C * 4);
    // padded rows (256 B): exactly 2 aligned cache lines per edge gather
    int cp = (ws_size >= fixedB + 2 * alup((size_t)N * 64 * 4)) ? 64 : 40;

    char* w = (char*)d_ws;
    auto alloc = [&](size_t bytes) {
        void* p = (void*)w;
        w += ((bytes + 255) / 256) * 256;
        return p;
    };
    int*   rp     = (int*)alloc((size_t)(N + 1) * 4);
    int*   cursor = (int*)alloc((size_t)(N + 1) * 4);
    int*   bsum   = (int*)alloc(1024);
    int2*  ep     = (int2*)alloc((size_t)E * 8);
    float* w2t    = (float*)alloc((size_t)H * C * 4);
    float* bufA   = (float*)alloc((size_t)N * cp * 4);
    float* bufB   = (float*)alloc((size_t)N * cp * 4);

    hipMemsetAsync(cursor, 0, (size_t)(N + 1) * 4, stream);

    k_count<<<(E + 255) / 256, 256, 0, stream>>>(ei + E, E, cursor);

    int n1 = N + 1;
    int NB = (n1 + 4095) / 4096;
    k_scan1<<<NB, 256, 0, stream>>>(cursor, n1, bsum);
    k_scan2<<<1, 64, 0, stream>>>(bsum, NB);
    k_scan3<<<NB, 256, 0, stream>>>(cursor, n1, bsum, rp);

    hipMemsetAsync(cursor, 0, (size_t)(N + 1) * 4, stream);
    k_fill<<<(E + 255) / 256, 256, 0, stream>>>(ei, ei + E, nrm, E, rp, cursor, ep);

    k_wt<<<(H * C + 255) / 256, 256, 0, stream>>>(W2, w2t);

    k_mlp<<<(N + TM - 1) / TM, 256, 0, stream>>>(x, W1, b1, g, be, mu, var, w2t, b2,
                                                 pw, pb, bufA, cp, out, N);

    int nodeBlocks64 = (N + 63) / 64;
    float* cur = bufA;
    float* nxt = bufB;
    for (int k = 0; k < KHOPS; k++) {
        k_hop<<<nodeBlocks64, 320, 0, stream>>>((const float4*)cur, (float4*)nxt, (float4*)out,
                                                rp, ep, cp / 4, pw, pb, N);
        float* tmp = cur; cur = nxt; nxt = tmp;
    }

    int nodeBlocks32 = (N + 31) / 32;
    k_lsm<<<nodeBlocks32, 320, 0, stream>>>((float4*)out, N);
}